// Round 1
// baseline (407.656 us; speedup 1.0000x reference)
//
#include <hip/hip_runtime.h>
#include <math.h>

#define NN 500000
#define CH 128
#define NG 1024

__device__ __forceinline__ float wred_max64(float v){
  #pragma unroll
  for (int o = 32; o; o >>= 1) v = fmaxf(v, __shfl_xor(v, o));
  return v;
}
__device__ __forceinline__ float wred_sum64(float v){
  #pragma unroll
  for (int o = 32; o; o >>= 1) v += __shfl_xor(v, o);
  return v;
}

// K0: segment boundaries. batch is sorted; start[g] = lower_bound(batch, g), start[NG] = NN.
// Hedge: reference declares int64; harness doc says int32. Detect at runtime:
// if data is int64 (little-endian), the high word of the last element (int32 index NN-1,
// NN-1 odd) is 0; if int32, batch[NN-1] is ~1023 (graph 1023 is nonempty w.h.p.).
__global__ void bounds_kernel(const int* __restrict__ batch, int* __restrict__ start){
  const int g = blockIdx.x * blockDim.x + threadIdx.x;
  if (g > NG) return;
  const bool is64 = (batch[NN - 1] == 0);
  if (g == NG){ start[NG] = NN; return; }
  int lo = 0, hi = NN;
  while (lo < hi){
    int mid = (lo + hi) >> 1;
    int v = is64 ? batch[2 * mid] : batch[mid];
    if (v < g) lo = mid + 1; else hi = mid;
  }
  start[g] = lo;
}

// K1: scores[n] = relu(x[n]@W1 + b1) . w2 + b2
// 256 threads; LDS: W1 (64KB) staged once + 64-row x tile (32KB) per tile.
// Thread tile: 8 nodes x 4 channels. Half-wave shuffle reduce over 32 channel-groups.
__global__ __launch_bounds__(256) void scores_kernel(
    const float* __restrict__ x, const float* __restrict__ W1,
    const float* __restrict__ b1, const float* __restrict__ w2,
    const float* __restrict__ b2, float* __restrict__ scores){
  extern __shared__ float4 smem4[];
  float* const W1s = reinterpret_cast<float*>(smem4);       // CH*CH floats
  float* const xs  = W1s + CH * CH;                         // 64*CH floats
  float* const b1s = xs + 64 * CH;                          // CH
  float* const w2s = b1s + CH;                              // CH

  const int tid = threadIdx.x;
  // stage W1 (once per block)
  for (int idx = tid; idx < CH * CH / 4; idx += 256)
    reinterpret_cast<float4*>(W1s)[idx] = reinterpret_cast<const float4*>(W1)[idx];
  if (tid < CH){ b1s[tid] = b1[tid]; w2s[tid] = w2[tid]; }
  const float b2v = b2[0];

  const int jg = tid & 31;          // channel group: j0 = jg*4
  const int ng = tid >> 5;          // node group: n0 = ng*8
  const int n0 = ng << 3;
  const int ntiles = (NN + 63) >> 6;

  for (int tile = blockIdx.x; tile < ntiles; tile += gridDim.x){
    const int base = tile << 6;
    const int rows = min(64, NN - base);
    __syncthreads();  // protect xs (and first-iter W1s)
    #pragma unroll
    for (int it = 0; it < 8; ++it){
      const int r = (tid >> 5) + (it << 3);
      if (r < rows)
        reinterpret_cast<float4*>(&xs[r * CH])[jg] =
          reinterpret_cast<const float4*>(&x[(size_t)(base + r) * CH])[jg];
    }
    __syncthreads();

    float acc[8][4] = {};
    for (int k = 0; k < CH; k += 4){
      float4 w[4];
      #pragma unroll
      for (int i = 0; i < 4; i++)
        w[i] = *reinterpret_cast<const float4*>(&W1s[(k + i) * CH + (jg << 2)]);
      const float* wp = reinterpret_cast<const float*>(w);
      #pragma unroll
      for (int n = 0; n < 8; n++){
        const float4 xv = *reinterpret_cast<const float4*>(&xs[(n0 + n) * CH + k]);
        const float xa[4] = {xv.x, xv.y, xv.z, xv.w};
        #pragma unroll
        for (int i = 0; i < 4; i++){
          #pragma unroll
          for (int j = 0; j < 4; j++)
            acc[n][j] = fmaf(xa[i], wp[i * 4 + j], acc[n][j]);
        }
      }
    }

    #pragma unroll
    for (int n = 0; n < 8; n++){
      float s = 0.f;
      #pragma unroll
      for (int j = 0; j < 4; j++){
        float h = acc[n][j] + b1s[(jg << 2) + j];
        h = fmaxf(h, 0.f);
        s = fmaf(h, w2s[(jg << 2) + j], s);
      }
      #pragma unroll
      for (int o = 16; o; o >>= 1) s += __shfl_xor(s, o);  // reduce within 32-lane half
      if (jg == 0 && (n0 + n) < rows) scores[base + n0 + n] = s + b2v;
    }
  }
}

// K2: per-graph softmax in place (scores -> attn)
__global__ __launch_bounds__(256) void softmax_kernel(
    float* __restrict__ sc, const int* __restrict__ start){
  const int g = blockIdx.x;
  const int s0 = start[g], s1 = start[g + 1];
  const int tid = threadIdx.x;
  __shared__ float tmp[4];
  __shared__ float bval;

  float m = -INFINITY;
  for (int i = s0 + tid; i < s1; i += 256) m = fmaxf(m, sc[i]);
  m = wred_max64(m);
  if ((tid & 63) == 0) tmp[tid >> 6] = m;
  __syncthreads();
  if (tid == 0) bval = fmaxf(fmaxf(tmp[0], tmp[1]), fmaxf(tmp[2], tmp[3]));
  __syncthreads();
  m = bval;

  float sum = 0.f;
  for (int i = s0 + tid; i < s1; i += 256){
    float e = __expf(sc[i] - m);
    sc[i] = e;
    sum += e;
  }
  sum = wred_sum64(sum);
  __syncthreads();
  if ((tid & 63) == 0) tmp[tid >> 6] = sum;
  __syncthreads();
  if (tid == 0) bval = tmp[0] + tmp[1] + tmp[2] + tmp[3];
  __syncthreads();
  const float inv = 1.f / bval;  // empty segment: inf, never used
  for (int i = s0 + tid; i < s1; i += 256) sc[i] *= inv;
}

// K3: out[g] = sum_i attn[i] * x[i]  over segment g
__global__ __launch_bounds__(256) void pool_kernel(
    const float* __restrict__ x, const float* __restrict__ attn,
    const int* __restrict__ start, float* __restrict__ out){
  const int g = blockIdx.x;
  const int s0 = start[g], s1 = start[g + 1];
  const int tid = threadIdx.x;
  const int c4 = tid & 31;   // float4 column
  const int rg = tid >> 5;   // row group 0..7

  float4 acc = make_float4(0.f, 0.f, 0.f, 0.f);
  for (int i = s0 + rg; i < s1; i += 8){
    const float a = attn[i];
    const float4 xv = reinterpret_cast<const float4*>(&x[(size_t)i * CH])[c4];
    acc.x = fmaf(a, xv.x, acc.x);
    acc.y = fmaf(a, xv.y, acc.y);
    acc.z = fmaf(a, xv.z, acc.z);
    acc.w = fmaf(a, xv.w, acc.w);
  }
  __shared__ float4 red[8][32];
  red[rg][c4] = acc;
  __syncthreads();
  if (rg < 4){
    float4 o = red[rg + 4][c4], m = red[rg][c4];
    m.x += o.x; m.y += o.y; m.z += o.z; m.w += o.w;
    red[rg][c4] = m;
  }
  __syncthreads();
  if (rg < 2){
    float4 o = red[rg + 2][c4], m = red[rg][c4];
    m.x += o.x; m.y += o.y; m.z += o.z; m.w += o.w;
    red[rg][c4] = m;
  }
  __syncthreads();
  if (rg == 0){
    float4 a0 = red[0][c4], a1 = red[1][c4];
    float4 r;
    r.x = a0.x + a1.x; r.y = a0.y + a1.y; r.z = a0.z + a1.z; r.w = a0.w + a1.w;
    reinterpret_cast<float4*>(&out[(size_t)g * CH])[c4] = r;
  }
}

extern "C" void kernel_launch(void* const* d_in, const int* in_sizes, int n_in,
                              void* d_out, int out_size, void* d_ws, size_t ws_size,
                              hipStream_t stream){
  const float* x    = (const float*)d_in[0];
  const int*   batch= (const int*)d_in[1];
  const float* W1   = (const float*)d_in[2];
  const float* b1   = (const float*)d_in[3];
  const float* w2   = (const float*)d_in[4];
  const float* b2   = (const float*)d_in[5];
  float* out = (float*)d_out;

  float* scores = (float*)d_ws;                                   // NN floats
  int*   start  = (int*)((char*)d_ws + (size_t)NN * sizeof(float)); // NG+1 ints

  bounds_kernel<<<(NG + 1 + 255) / 256, 256, 0, stream>>>(batch, start);

  const size_t smem = (size_t)(CH * CH + 64 * CH + 2 * CH) * sizeof(float);
  scores_kernel<<<256, 256, smem, stream>>>(x, W1, b1, w2, b2, scores);

  softmax_kernel<<<NG, 256, 0, stream>>>(scores, start);
  pool_kernel<<<NG, 256, 0, stream>>>(x, scores, start, out);
}

// Round 2
// 234.480 us; speedup vs baseline: 1.7386x; 1.7386x over previous
//
#include <hip/hip_runtime.h>
#include <math.h>

#define NN 500000
#define CH 128
#define NG 1024
#define NTILES ((NN + 127) >> 7)   // 3907 tiles of 128 rows

typedef __attribute__((ext_vector_type(8))) short short8v;
typedef __attribute__((ext_vector_type(4))) float f32x4;

__device__ __forceinline__ float wred_max64(float v){
  #pragma unroll
  for (int o = 32; o; o >>= 1) v = fmaxf(v, __shfl_xor(v, o));
  return v;
}
__device__ __forceinline__ float wred_sum64(float v){
  #pragma unroll
  for (int o = 32; o; o >>= 1) v += __shfl_xor(v, o);
  return v;
}

// K0: segment boundaries. batch sorted; start[g] = lower_bound(batch, g).
// int64-vs-int32 runtime hedge (reference declares int64).
__global__ void bounds_kernel(const int* __restrict__ batch, int* __restrict__ start){
  const int g = blockIdx.x * blockDim.x + threadIdx.x;
  if (g > NG) return;
  const bool is64 = (batch[NN - 1] == 0);
  if (g == NG){ start[NG] = NN; return; }
  int lo = 0, hi = NN;
  while (lo < hi){
    int mid = (lo + hi) >> 1;
    int v = is64 ? batch[2 * mid] : batch[mid];
    if (v < g) lo = mid + 1; else hi = mid;
  }
  start[g] = lo;
}

// K1: scores = relu(x@W1 + b1) . w2 + b2 via bf16-split MFMA.
// 4 waves/block, 32 rows/wave (2 x 16-row MFMA subtiles), 128 rows/block-tile.
// W1^T staged in LDS as bf16 hi/lo, XOR-swizzled for conflict-free ds_read_b128.
__global__ __launch_bounds__(256, 2) void scores_mfma(
    const float* __restrict__ x, const float* __restrict__ W1,
    const float* __restrict__ b1, const float* __restrict__ w2,
    const float* __restrict__ b2, float* __restrict__ scores)
{
  __shared__ unsigned short Wh[CH * CH];   // W1^T hi: [n][k], row = 256B
  __shared__ unsigned short Wl[CH * CH];   // W1^T lo
  __shared__ float b1s[CH], w2s[CH];

  const int tid = threadIdx.x;

  // Stage W1 transposed + hi/lo split.
  // Consecutive threads take consecutive k-chunks (same n) -> contiguous LDS writes.
  for (int c = tid; c < CH * 16; c += 256){
    const int n  = c >> 4;          // out-channel 0..127
    const int k0 = (c & 15) << 3;   // 0,8,...,120
    unsigned short hv[8], lv[8];
    #pragma unroll
    for (int i = 0; i < 8; i++){
      const float f = W1[(size_t)(k0 + i) * CH + n];
      const unsigned u = __float_as_uint(f);
      hv[i] = (unsigned short)(u >> 16);
      const float hif = __uint_as_float(u & 0xffff0000u);
      const float lof = f - hif;
      lv[i] = (unsigned short)(__float_as_uint(lof) >> 16);
    }
    int byte = n * 256 + k0 * 2;
    byte ^= (n & 7) << 4;           // XOR swizzle (16B granule)
    *reinterpret_cast<short8v*>(reinterpret_cast<char*>(Wh) + byte) =
        *reinterpret_cast<short8v*>(hv);
    *reinterpret_cast<short8v*>(reinterpret_cast<char*>(Wl) + byte) =
        *reinterpret_cast<short8v*>(lv);
  }
  if (tid < CH){ b1s[tid] = b1[tid]; w2s[tid] = w2[tid]; }
  __syncthreads();   // LDS is read-only below; no further barriers needed

  const float b2v = b2[0];
  const int w   = tid >> 6;    // wave 0..3
  const int l   = tid & 63;
  const int l15 = l & 15;
  const int g   = l >> 4;      // 0..3

  for (int tile = blockIdx.x; tile < NTILES; tile += gridDim.x){
    const int rowbase = (tile << 7) + (w << 5);   // this wave's 32 rows
    f32x4 acc[2][8];
    #pragma unroll
    for (int a = 0; a < 2; a++)
      #pragma unroll
      for (int b = 0; b < 8; b++) acc[a][b] = (f32x4)0.f;

    #pragma unroll
    for (int kc = 0; kc < 4; kc++){
      // A fragments: lane l holds x[row = l&15][k = 32*kc + 8*(l>>4) + j]
      short8v Ah[2], Al[2];
      #pragma unroll
      for (int nt = 0; nt < 2; nt++){
        int row = rowbase + nt * 16 + l15;
        row = row < NN ? row : NN - 1;            // clamp (stores guarded)
        const float* xp = x + (size_t)row * CH + kc * 32 + g * 8;
        float fv[8];
        *reinterpret_cast<float4*>(fv)     = *reinterpret_cast<const float4*>(xp);
        *reinterpret_cast<float4*>(fv + 4) = *reinterpret_cast<const float4*>(xp + 4);
        unsigned short hv[8], lv[8];
        #pragma unroll
        for (int j = 0; j < 8; j++){
          const unsigned u = __float_as_uint(fv[j]);
          hv[j] = (unsigned short)(u >> 16);
          const float hif = __uint_as_float(u & 0xffff0000u);
          const float lof = fv[j] - hif;
          lv[j] = (unsigned short)(__float_as_uint(lof) >> 16);
        }
        Ah[nt] = *reinterpret_cast<short8v*>(hv);
        Al[nt] = *reinterpret_cast<short8v*>(lv);
      }
      #pragma unroll
      for (int ct = 0; ct < 8; ct++){
        const int n = ct * 16 + l15;
        int byte = n * 256 + kc * 64 + g * 16;
        byte ^= (n & 7) << 4;
        const short8v Bh = *reinterpret_cast<const short8v*>(
            reinterpret_cast<const char*>(Wh) + byte);
        const short8v Bl = *reinterpret_cast<const short8v*>(
            reinterpret_cast<const char*>(Wl) + byte);
        #pragma unroll
        for (int nt = 0; nt < 2; nt++){
          acc[nt][ct] = __builtin_amdgcn_mfma_f32_16x16x32_bf16(Ah[nt], Bh, acc[nt][ct], 0, 0, 0);
          acc[nt][ct] = __builtin_amdgcn_mfma_f32_16x16x32_bf16(Al[nt], Bh, acc[nt][ct], 0, 0, 0);
          acc[nt][ct] = __builtin_amdgcn_mfma_f32_16x16x32_bf16(Ah[nt], Bl, acc[nt][ct], 0, 0, 0);
        }
      }
    }

    // Epilogue: h = relu(H + b1); partial s = h . w2 over this lane's 8 cols;
    // reduce across the 16 lanes of each row group; lane n==base writes.
    #pragma unroll
    for (int nt = 0; nt < 2; nt++){
      #pragma unroll
      for (int r = 0; r < 4; r++){
        float s = 0.f;
        #pragma unroll
        for (int ct = 0; ct < 8; ct++){
          const int n = ct * 16 + l15;
          float h = acc[nt][ct][r] + b1s[n];
          h = fmaxf(h, 0.f);
          s = fmaf(h, w2s[n], s);
        }
        s += __shfl_xor(s, 1); s += __shfl_xor(s, 2);
        s += __shfl_xor(s, 4); s += __shfl_xor(s, 8);
        const int grow = rowbase + nt * 16 + g * 4 + r;  // D: row = 4*(l>>4)+r
        if (l15 == 0 && grow < NN) scores[grow] = s + b2v;
      }
    }
  }
}

// K2: per-graph softmax in place (scores -> attn)
__global__ __launch_bounds__(256) void softmax_kernel(
    float* __restrict__ sc, const int* __restrict__ start){
  const int g = blockIdx.x;
  const int s0 = start[g], s1 = start[g + 1];
  const int tid = threadIdx.x;
  __shared__ float tmp[4];
  __shared__ float bval;

  float m = -INFINITY;
  for (int i = s0 + tid; i < s1; i += 256) m = fmaxf(m, sc[i]);
  m = wred_max64(m);
  if ((tid & 63) == 0) tmp[tid >> 6] = m;
  __syncthreads();
  if (tid == 0) bval = fmaxf(fmaxf(tmp[0], tmp[1]), fmaxf(tmp[2], tmp[3]));
  __syncthreads();
  m = bval;

  float sum = 0.f;
  for (int i = s0 + tid; i < s1; i += 256){
    float e = __expf(sc[i] - m);
    sc[i] = e;
    sum += e;
  }
  sum = wred_sum64(sum);
  __syncthreads();
  if ((tid & 63) == 0) tmp[tid >> 6] = sum;
  __syncthreads();
  if (tid == 0) bval = tmp[0] + tmp[1] + tmp[2] + tmp[3];
  __syncthreads();
  const float inv = 1.f / bval;
  for (int i = s0 + tid; i < s1; i += 256) sc[i] *= inv;
}

// K3: out[g] = sum_i attn[i] * x[i]  over segment g
__global__ __launch_bounds__(256) void pool_kernel(
    const float* __restrict__ x, const float* __restrict__ attn,
    const int* __restrict__ start, float* __restrict__ out){
  const int g = blockIdx.x;
  const int s0 = start[g], s1 = start[g + 1];
  const int tid = threadIdx.x;
  const int c4 = tid & 31;   // float4 column
  const int rg = tid >> 5;   // row group 0..7

  float4 acc = make_float4(0.f, 0.f, 0.f, 0.f);
  for (int i = s0 + rg; i < s1; i += 8){
    const float a = attn[i];
    const float4 xv = reinterpret_cast<const float4*>(&x[(size_t)i * CH])[c4];
    acc.x = fmaf(a, xv.x, acc.x);
    acc.y = fmaf(a, xv.y, acc.y);
    acc.z = fmaf(a, xv.z, acc.z);
    acc.w = fmaf(a, xv.w, acc.w);
  }
  __shared__ float4 red[8][32];
  red[rg][c4] = acc;
  __syncthreads();
  if (rg < 4){
    float4 o = red[rg + 4][c4], m = red[rg][c4];
    m.x += o.x; m.y += o.y; m.z += o.z; m.w += o.w;
    red[rg][c4] = m;
  }
  __syncthreads();
  if (rg < 2){
    float4 o = red[rg + 2][c4], m = red[rg][c4];
    m.x += o.x; m.y += o.y; m.z += o.z; m.w += o.w;
    red[rg][c4] = m;
  }
  __syncthreads();
  if (rg == 0){
    float4 a0 = red[0][c4], a1 = red[1][c4];
    float4 r;
    r.x = a0.x + a1.x; r.y = a0.y + a1.y; r.z = a0.z + a1.z; r.w = a0.w + a1.w;
    reinterpret_cast<float4*>(&out[(size_t)g * CH])[c4] = r;
  }
}

extern "C" void kernel_launch(void* const* d_in, const int* in_sizes, int n_in,
                              void* d_out, int out_size, void* d_ws, size_t ws_size,
                              hipStream_t stream){
  const float* x    = (const float*)d_in[0];
  const int*   batch= (const int*)d_in[1];
  const float* W1   = (const float*)d_in[2];
  const float* b1   = (const float*)d_in[3];
  const float* w2   = (const float*)d_in[4];
  const float* b2   = (const float*)d_in[5];
  float* out = (float*)d_out;

  float* scores = (float*)d_ws;                                     // NN floats
  int*   start  = (int*)((char*)d_ws + (size_t)NN * sizeof(float)); // NG+1 ints

  bounds_kernel<<<(NG + 1 + 255) / 256, 256, 0, stream>>>(batch, start);
  scores_mfma<<<512, 256, 0, stream>>>(x, W1, b1, w2, b2, scores);
  softmax_kernel<<<NG, 256, 0, stream>>>(scores, start);
  pool_kernel<<<NG, 256, 0, stream>>>(x, scores, start, out);
}

// Round 3
// 215.737 us; speedup vs baseline: 1.8896x; 1.0869x over previous
//
#include <hip/hip_runtime.h>
#include <math.h>

#define NN 500000
#define CH 128
#define NG 1024
#define NTILES ((NN + 127) >> 7)   // 3907 tiles of 128 rows

typedef __attribute__((ext_vector_type(8))) short short8v;
typedef __attribute__((ext_vector_type(4))) float f32x4;

__device__ __forceinline__ float wred_max64(float v){
  #pragma unroll
  for (int o = 32; o; o >>= 1) v = fmaxf(v, __shfl_xor(v, o));
  return v;
}
__device__ __forceinline__ float wred_sum64(float v){
  #pragma unroll
  for (int o = 32; o; o >>= 1) v += __shfl_xor(v, o);
  return v;
}

__device__ __forceinline__ void bf16_split(float f, unsigned short& h, unsigned short& l){
  const unsigned u = __float_as_uint(f);
  h = (unsigned short)(u >> 16);
  const float hif = __uint_as_float(u & 0xffff0000u);
  const float lof = f - hif;
  l = (unsigned short)(__float_as_uint(lof) >> 16);
}

// Prep: (a) threads 0..2047: transpose + bf16-hi/lo-split W1 into Wg, already in
// the swizzled LDS byte order (hi at [0,32KB), lo at [32KB,64KB)).
// (b) threads 2048..3072: segment boundaries (lower_bound on sorted batch).
__global__ __launch_bounds__(256) void prep_kernel(
    const float* __restrict__ W1, unsigned short* __restrict__ Wg,
    const int* __restrict__ batch, int* __restrict__ start){
  const int t = blockIdx.x * 256 + threadIdx.x;
  if (t < 2048){
    const int n  = t >> 4;          // out-channel 0..127
    const int k0 = (t & 15) << 3;   // 0,8,...,120
    unsigned short hv[8], lv[8];
    #pragma unroll
    for (int i = 0; i < 8; i++)
      bf16_split(W1[(size_t)(k0 + i) * CH + n], hv[i], lv[i]);
    const int byte = (n * 256 + k0 * 2) ^ ((n & 7) << 4);   // XOR swizzle, 16B granule
    *reinterpret_cast<short8v*>(reinterpret_cast<char*>(Wg) + byte) =
        *reinterpret_cast<short8v*>(hv);
    *reinterpret_cast<short8v*>(reinterpret_cast<char*>(Wg) + 32768 + byte) =
        *reinterpret_cast<short8v*>(lv);
  } else if (t <= 2048 + NG){
    const int g = t - 2048;
    const bool is64 = (batch[NN - 1] == 0);   // int64-vs-int32 runtime hedge
    if (g == NG){ start[NG] = NN; return; }
    int lo = 0, hi = NN;
    while (lo < hi){
      int mid = (lo + hi) >> 1;
      int v = is64 ? batch[2 * mid] : batch[mid];
      if (v < g) lo = mid + 1; else hi = mid;
    }
    start[g] = lo;
  }
}

// K1: scores = relu(x@W1 + b1) . w2 + b2 via 3-term bf16-split MFMA.
// 4 waves/block, 32 rows/wave, 128 rows/block-tile. W1 staged from pre-split
// Wg with linear coalesced copies (no gather, no herd amplification).
__global__ __launch_bounds__(256, 2) void scores_mfma(
    const float* __restrict__ x, const unsigned short* __restrict__ Wg,
    const float* __restrict__ b1, const float* __restrict__ w2,
    const float* __restrict__ b2, float* __restrict__ scores)
{
  __shared__ unsigned short WB[2 * CH * CH];   // hi | lo, swizzled, 64KB
  __shared__ float b1s[CH], w2s[CH];

  const int tid = threadIdx.x;

  // Linear, coalesced, conflict-free staging of pre-split W1.
  {
    const short8v* __restrict__ src = reinterpret_cast<const short8v*>(Wg);
    short8v* dst = reinterpret_cast<short8v*>(WB);
    #pragma unroll
    for (int it = 0; it < 16; ++it)
      dst[it * 256 + tid] = src[it * 256 + tid];
  }
  if (tid < CH){ b1s[tid] = b1[tid]; w2s[tid] = w2[tid]; }
  __syncthreads();   // LDS read-only below; no further barriers

  const char* const WhB = reinterpret_cast<const char*>(WB);
  const char* const WlB = reinterpret_cast<const char*>(WB) + 32768;

  const float b2v = b2[0];
  const int w   = tid >> 6;    // wave 0..3
  const int l   = tid & 63;
  const int l15 = l & 15;
  const int g   = l >> 4;      // 0..3

  for (int tile = blockIdx.x; tile < NTILES; tile += gridDim.x){
    const int rowbase = (tile << 7) + (w << 5);   // this wave's 32 rows

    // Hoist ALL A-tile loads: 16 float4 per lane, issued before any compute.
    float4 raw[2][4][2];
    #pragma unroll
    for (int nt = 0; nt < 2; nt++){
      int row = rowbase + nt * 16 + l15;
      row = row < NN ? row : NN - 1;            // clamp (stores guarded)
      const float4* xp = reinterpret_cast<const float4*>(x + (size_t)row * CH);
      #pragma unroll
      for (int kc = 0; kc < 4; kc++){
        raw[nt][kc][0] = xp[kc * 8 + g * 2];
        raw[nt][kc][1] = xp[kc * 8 + g * 2 + 1];
      }
    }

    f32x4 acc[2][8];
    #pragma unroll
    for (int a = 0; a < 2; a++)
      #pragma unroll
      for (int b = 0; b < 8; b++) acc[a][b] = (f32x4)0.f;

    #pragma unroll
    for (int kc = 0; kc < 4; kc++){
      // A fragments: lane l holds x[row = l&15][k = 32*kc + 8*(l>>4) + j]
      short8v Ah[2], Al[2];
      #pragma unroll
      for (int nt = 0; nt < 2; nt++){
        float fv[8];
        *reinterpret_cast<float4*>(fv)     = raw[nt][kc][0];
        *reinterpret_cast<float4*>(fv + 4) = raw[nt][kc][1];
        unsigned short hv[8], lv[8];
        #pragma unroll
        for (int j = 0; j < 8; j++) bf16_split(fv[j], hv[j], lv[j]);
        Ah[nt] = *reinterpret_cast<short8v*>(hv);
        Al[nt] = *reinterpret_cast<short8v*>(lv);
      }
      #pragma unroll
      for (int ct = 0; ct < 8; ct++){
        const int n = ct * 16 + l15;
        const int byte = (n * 256 + kc * 64 + g * 16) ^ ((n & 7) << 4);
        const short8v Bh = *reinterpret_cast<const short8v*>(WhB + byte);
        const short8v Bl = *reinterpret_cast<const short8v*>(WlB + byte);
        #pragma unroll
        for (int nt = 0; nt < 2; nt++){
          acc[nt][ct] = __builtin_amdgcn_mfma_f32_16x16x32_bf16(Ah[nt], Bh, acc[nt][ct], 0, 0, 0);
          acc[nt][ct] = __builtin_amdgcn_mfma_f32_16x16x32_bf16(Al[nt], Bh, acc[nt][ct], 0, 0, 0);
          acc[nt][ct] = __builtin_amdgcn_mfma_f32_16x16x32_bf16(Ah[nt], Bl, acc[nt][ct], 0, 0, 0);
        }
      }
    }

    // Epilogue: h = relu(H + b1); s = h.w2 reduced across 16 lanes per row.
    #pragma unroll
    for (int nt = 0; nt < 2; nt++){
      #pragma unroll
      for (int r = 0; r < 4; r++){
        float s = 0.f;
        #pragma unroll
        for (int ct = 0; ct < 8; ct++){
          const int n = ct * 16 + l15;
          float h = acc[nt][ct][r] + b1s[n];
          h = fmaxf(h, 0.f);
          s = fmaf(h, w2s[n], s);
        }
        s += __shfl_xor(s, 1); s += __shfl_xor(s, 2);
        s += __shfl_xor(s, 4); s += __shfl_xor(s, 8);
        const int grow = rowbase + nt * 16 + g * 4 + r;  // D: row = 4*(l>>4)+r
        if (l15 == 0 && grow < NN) scores[grow] = s + b2v;
      }
    }
  }
}

// K2: per-graph softmax in place (scores -> attn)
__global__ __launch_bounds__(256) void softmax_kernel(
    float* __restrict__ sc, const int* __restrict__ start){
  const int g = blockIdx.x;
  const int s0 = start[g], s1 = start[g + 1];
  const int tid = threadIdx.x;
  __shared__ float tmp[4];
  __shared__ float bval;

  float m = -INFINITY;
  for (int i = s0 + tid; i < s1; i += 256) m = fmaxf(m, sc[i]);
  m = wred_max64(m);
  if ((tid & 63) == 0) tmp[tid >> 6] = m;
  __syncthreads();
  if (tid == 0) bval = fmaxf(fmaxf(tmp[0], tmp[1]), fmaxf(tmp[2], tmp[3]));
  __syncthreads();
  m = bval;

  float sum = 0.f;
  for (int i = s0 + tid; i < s1; i += 256){
    float e = __expf(sc[i] - m);
    sc[i] = e;
    sum += e;
  }
  sum = wred_sum64(sum);
  __syncthreads();
  if ((tid & 63) == 0) tmp[tid >> 6] = sum;
  __syncthreads();
  if (tid == 0) bval = tmp[0] + tmp[1] + tmp[2] + tmp[3];
  __syncthreads();
  const float inv = 1.f / bval;
  for (int i = s0 + tid; i < s1; i += 256) sc[i] *= inv;
}

// K3: out[g] = sum_i attn[i] * x[i]  over segment g
__global__ __launch_bounds__(256) void pool_kernel(
    const float* __restrict__ x, const float* __restrict__ attn,
    const int* __restrict__ start, float* __restrict__ out){
  const int g = blockIdx.x;
  const int s0 = start[g], s1 = start[g + 1];
  const int tid = threadIdx.x;
  const int c4 = tid & 31;   // float4 column
  const int rg = tid >> 5;   // row group 0..7

  float4 acc = make_float4(0.f, 0.f, 0.f, 0.f);
  for (int i = s0 + rg; i < s1; i += 8){
    const float a = attn[i];
    const float4 xv = reinterpret_cast<const float4*>(&x[(size_t)i * CH])[c4];
    acc.x = fmaf(a, xv.x, acc.x);
    acc.y = fmaf(a, xv.y, acc.y);
    acc.z = fmaf(a, xv.z, acc.z);
    acc.w = fmaf(a, xv.w, acc.w);
  }
  __shared__ float4 red[8][32];
  red[rg][c4] = acc;
  __syncthreads();
  if (rg < 4){
    float4 o = red[rg + 4][c4], m = red[rg][c4];
    m.x += o.x; m.y += o.y; m.z += o.z; m.w += o.w;
    red[rg][c4] = m;
  }
  __syncthreads();
  if (rg < 2){
    float4 o = red[rg + 2][c4], m = red[rg][c4];
    m.x += o.x; m.y += o.y; m.z += o.z; m.w += o.w;
    red[rg][c4] = m;
  }
  __syncthreads();
  if (rg == 0){
    float4 a0 = red[0][c4], a1 = red[1][c4];
    float4 r;
    r.x = a0.x + a1.x; r.y = a0.y + a1.y; r.z = a0.z + a1.z; r.w = a0.w + a1.w;
    reinterpret_cast<float4*>(&out[(size_t)g * CH])[c4] = r;
  }
}

extern "C" void kernel_launch(void* const* d_in, const int* in_sizes, int n_in,
                              void* d_out, int out_size, void* d_ws, size_t ws_size,
                              hipStream_t stream){
  const float* x    = (const float*)d_in[0];
  const int*   batch= (const int*)d_in[1];
  const float* W1   = (const float*)d_in[2];
  const float* b1   = (const float*)d_in[3];
  const float* w2   = (const float*)d_in[4];
  const float* b2   = (const float*)d_in[5];
  float* out = (float*)d_out;

  float* scores = (float*)d_ws;                                     // NN floats
  int*   start  = (int*)((char*)d_ws + (size_t)NN * sizeof(float)); // NG+1 ints
  // Pre-split W1 lives at the END of the workspace (64KB, 256B-aligned).
  unsigned short* Wg = (unsigned short*)((char*)d_ws + ((ws_size - 65536) & ~(size_t)255));

  prep_kernel<<<13, 256, 0, stream>>>(W1, Wg, batch, start);
  scores_mfma<<<512, 256, 0, stream>>>(x, Wg, b1, w2, b2, scores);
  softmax_kernel<<<NG, 256, 0, stream>>>(scores, start);
  pool_kernel<<<NG, 256, 0, stream>>>(x, scores, start, out);
}

// Round 4
// 214.073 us; speedup vs baseline: 1.9043x; 1.0078x over previous
//
#include <hip/hip_runtime.h>
#include <math.h>

#define NN 500000
#define CH 128
#define NG 1024
#define NTILES ((NN + 127) >> 7)   // 3907 tiles of 128 rows

typedef __attribute__((ext_vector_type(8))) short short8v;
typedef __attribute__((ext_vector_type(4))) float f32x4;

__device__ __forceinline__ float wred_max64(float v){
  #pragma unroll
  for (int o = 32; o; o >>= 1) v = fmaxf(v, __shfl_xor(v, o));
  return v;
}

__device__ __forceinline__ void bf16_split(float f, unsigned short& h, unsigned short& l){
  const unsigned u = __float_as_uint(f);
  h = (unsigned short)(u >> 16);
  const float hif = __uint_as_float(u & 0xffff0000u);
  const float lof = f - hif;
  l = (unsigned short)(__float_as_uint(lof) >> 16);
}

// Prep: (a) threads 0..2047: transpose + bf16-hi/lo-split W1 into Wg, already in
// swizzled LDS byte order. (b) threads 2048..3072: segment boundaries.
__global__ __launch_bounds__(256) void prep_kernel(
    const float* __restrict__ W1, unsigned short* __restrict__ Wg,
    const int* __restrict__ batch, int* __restrict__ start){
  const int t = blockIdx.x * 256 + threadIdx.x;
  if (t < 2048){
    const int n  = t >> 4;          // out-channel 0..127
    const int k0 = (t & 15) << 3;   // 0,8,...,120
    unsigned short hv[8], lv[8];
    #pragma unroll
    for (int i = 0; i < 8; i++)
      bf16_split(W1[(size_t)(k0 + i) * CH + n], hv[i], lv[i]);
    const int byte = (n * 256 + k0 * 2) ^ ((n & 7) << 4);   // XOR swizzle, 16B granule
    *reinterpret_cast<short8v*>(reinterpret_cast<char*>(Wg) + byte) =
        *reinterpret_cast<short8v*>(hv);
    *reinterpret_cast<short8v*>(reinterpret_cast<char*>(Wg) + 32768 + byte) =
        *reinterpret_cast<short8v*>(lv);
  } else if (t <= 2048 + NG){
    const int g = t - 2048;
    const bool is64 = (batch[NN - 1] == 0);   // int64-vs-int32 runtime hedge
    if (g == NG){ start[NG] = NN; return; }
    int lo = 0, hi = NN;
    while (lo < hi){
      int mid = (lo + hi) >> 1;
      int v = is64 ? batch[2 * mid] : batch[mid];
      if (v < g) lo = mid + 1; else hi = mid;
    }
    start[g] = lo;
  }
}

// K1: scores = relu(x@W1 + b1) . w2 + b2 via 3-term bf16-split MFMA.
// 4 waves/block, 32 rows/wave, 128 rows/block-tile. Per-kc software pipeline
// with explicit 2-deep load buffer (all static indices) -> no scratch spill.
__global__ __launch_bounds__(256, 2) void scores_mfma(
    const float* __restrict__ x, const unsigned short* __restrict__ Wg,
    const float* __restrict__ b1, const float* __restrict__ w2,
    const float* __restrict__ b2, float* __restrict__ scores)
{
  __shared__ unsigned short WB[2 * CH * CH];   // hi | lo, swizzled, 64KB
  __shared__ float b1s[CH], w2s[CH];

  const int tid = threadIdx.x;
  {
    const short8v* __restrict__ src = reinterpret_cast<const short8v*>(Wg);
    short8v* dst = reinterpret_cast<short8v*>(WB);
    #pragma unroll
    for (int it = 0; it < 16; ++it)
      dst[it * 256 + tid] = src[it * 256 + tid];
  }
  if (tid < CH){ b1s[tid] = b1[tid]; w2s[tid] = w2[tid]; }
  __syncthreads();   // LDS read-only below; no further barriers

  const char* const WhB = reinterpret_cast<const char*>(WB);
  const char* const WlB = reinterpret_cast<const char*>(WB) + 32768;

  const float b2v = b2[0];
  const int w   = tid >> 6;    // wave 0..3
  const int l   = tid & 63;
  const int l15 = l & 15;
  const int g   = l >> 4;      // 0..3

  for (int tile = blockIdx.x; tile < NTILES; tile += gridDim.x){
    const int rowbase = (tile << 7) + (w << 5);   // this wave's 32 rows
    const float4* xp[2];
    #pragma unroll
    for (int nt = 0; nt < 2; nt++){
      int row = rowbase + nt * 16 + l15;
      row = row < NN ? row : NN - 1;              // clamp (stores guarded)
      xp[nt] = reinterpret_cast<const float4*>(x + (size_t)row * CH);
    }

    f32x4 acc[2][8];
    #pragma unroll
    for (int a = 0; a < 2; a++)
      #pragma unroll
      for (int b = 0; b < 8; b++) acc[a][b] = (f32x4)0.f;

    float4 raw[2][2][2];                           // [buf][nt][half]
    #pragma unroll
    for (int nt = 0; nt < 2; nt++){
      raw[0][nt][0] = xp[nt][g * 2];
      raw[0][nt][1] = xp[nt][g * 2 + 1];
    }

    #pragma unroll
    for (int kc = 0; kc < 4; kc++){
      const int cur = kc & 1, nxt = cur ^ 1;
      // prefetch next kc chunk (independent of conversion below)
      if (kc < 3){
        #pragma unroll
        for (int nt = 0; nt < 2; nt++){
          raw[nxt][nt][0] = xp[nt][(kc + 1) * 8 + g * 2];
          raw[nxt][nt][1] = xp[nt][(kc + 1) * 8 + g * 2 + 1];
        }
      }
      // convert current chunk: lane l holds x[row=l&15][k=32*kc+8*(l>>4)+j]
      short8v Ah[2], Al[2];
      #pragma unroll
      for (int nt = 0; nt < 2; nt++){
        float fv[8];
        *reinterpret_cast<float4*>(fv)     = raw[cur][nt][0];
        *reinterpret_cast<float4*>(fv + 4) = raw[cur][nt][1];
        unsigned short hv[8], lv[8];
        #pragma unroll
        for (int j = 0; j < 8; j++) bf16_split(fv[j], hv[j], lv[j]);
        Ah[nt] = *reinterpret_cast<short8v*>(hv);
        Al[nt] = *reinterpret_cast<short8v*>(lv);
      }
      #pragma unroll
      for (int ct = 0; ct < 8; ct++){
        const int n = ct * 16 + l15;
        const int byte = (n * 256 + kc * 64 + g * 16) ^ ((n & 7) << 4);
        const short8v Bh = *reinterpret_cast<const short8v*>(WhB + byte);
        const short8v Bl = *reinterpret_cast<const short8v*>(WlB + byte);
        #pragma unroll
        for (int nt = 0; nt < 2; nt++){
          acc[nt][ct] = __builtin_amdgcn_mfma_f32_16x16x32_bf16(Ah[nt], Bh, acc[nt][ct], 0, 0, 0);
          acc[nt][ct] = __builtin_amdgcn_mfma_f32_16x16x32_bf16(Al[nt], Bh, acc[nt][ct], 0, 0, 0);
          acc[nt][ct] = __builtin_amdgcn_mfma_f32_16x16x32_bf16(Ah[nt], Bl, acc[nt][ct], 0, 0, 0);
        }
      }
    }

    // Epilogue: h = relu(H + b1); s = h.w2 reduced across 16 lanes per row.
    #pragma unroll
    for (int nt = 0; nt < 2; nt++){
      #pragma unroll
      for (int r = 0; r < 4; r++){
        float s = 0.f;
        #pragma unroll
        for (int ct = 0; ct < 8; ct++){
          const int n = ct * 16 + l15;
          float h = acc[nt][ct][r] + b1s[n];
          h = fmaxf(h, 0.f);
          s = fmaf(h, w2s[n], s);
        }
        s += __shfl_xor(s, 1); s += __shfl_xor(s, 2);
        s += __shfl_xor(s, 4); s += __shfl_xor(s, 8);
        const int grow = rowbase + nt * 16 + g * 4 + r;  // D: row = 4*(l>>4)+r
        if (l15 == 0 && grow < NN) scores[grow] = s + b2v;
      }
    }
  }
}

// K3 (fused softmax+pool): out[g] = sum_i e_i * x_i / sum_i e_i,
// e_i = exp(s_i - max_g). One block per graph.
__global__ __launch_bounds__(256) void pool_kernel(
    const float* __restrict__ x, const float* __restrict__ sc,
    const int* __restrict__ start, float* __restrict__ out){
  const int g = blockIdx.x;
  const int s0 = start[g], s1 = start[g + 1];
  const int tid = threadIdx.x;

  __shared__ float tmp[4];
  __shared__ float bval;

  // Phase 1: segment max of raw scores
  float m = -INFINITY;
  for (int i = s0 + tid; i < s1; i += 256) m = fmaxf(m, sc[i]);
  m = wred_max64(m);
  if ((tid & 63) == 0) tmp[tid >> 6] = m;
  __syncthreads();
  if (tid == 0) bval = fmaxf(fmaxf(tmp[0], tmp[1]), fmaxf(tmp[2], tmp[3]));
  __syncthreads();
  m = bval;

  // Phase 2: weighted accumulate (denominator replicated per c4 column)
  const int c4 = tid & 31;   // float4 column
  const int rg = tid >> 5;   // row group 0..7
  float4 acc = make_float4(0.f, 0.f, 0.f, 0.f);
  float den = 0.f;
  for (int i = s0 + rg; i < s1; i += 8){
    const float e = __expf(sc[i] - m);
    den += e;
    const float4 xv = reinterpret_cast<const float4*>(&x[(size_t)i * CH])[c4];
    acc.x = fmaf(e, xv.x, acc.x);
    acc.y = fmaf(e, xv.y, acc.y);
    acc.z = fmaf(e, xv.z, acc.z);
    acc.w = fmaf(e, xv.w, acc.w);
  }

  __shared__ float4 red[8][32];
  __shared__ float redd[8][32];
  red[rg][c4] = acc;
  redd[rg][c4] = den;
  __syncthreads();
  if (rg < 4){
    float4 o = red[rg + 4][c4], mm = red[rg][c4];
    mm.x += o.x; mm.y += o.y; mm.z += o.z; mm.w += o.w;
    red[rg][c4] = mm;
    redd[rg][c4] += redd[rg + 4][c4];
  }
  __syncthreads();
  if (rg < 2){
    float4 o = red[rg + 2][c4], mm = red[rg][c4];
    mm.x += o.x; mm.y += o.y; mm.z += o.z; mm.w += o.w;
    red[rg][c4] = mm;
    redd[rg][c4] += redd[rg + 2][c4];
  }
  __syncthreads();
  if (rg == 0){
    float4 a0 = red[0][c4], a1 = red[1][c4];
    const float d = redd[0][c4] + redd[1][c4];
    const float inv = d > 0.f ? 1.f / d : 0.f;
    float4 r;
    r.x = (a0.x + a1.x) * inv; r.y = (a0.y + a1.y) * inv;
    r.z = (a0.z + a1.z) * inv; r.w = (a0.w + a1.w) * inv;
    reinterpret_cast<float4*>(&out[(size_t)g * CH])[c4] = r;
  }
}

extern "C" void kernel_launch(void* const* d_in, const int* in_sizes, int n_in,
                              void* d_out, int out_size, void* d_ws, size_t ws_size,
                              hipStream_t stream){
  const float* x    = (const float*)d_in[0];
  const int*   batch= (const int*)d_in[1];
  const float* W1   = (const float*)d_in[2];
  const float* b1   = (const float*)d_in[3];
  const float* w2   = (const float*)d_in[4];
  const float* b2   = (const float*)d_in[5];
  float* out = (float*)d_out;

  float* scores = (float*)d_ws;                                     // NN floats
  int*   start  = (int*)((char*)d_ws + (size_t)NN * sizeof(float)); // NG+1 ints
  unsigned short* Wg = (unsigned short*)((char*)d_ws + ((ws_size - 65536) & ~(size_t)255));

  prep_kernel<<<13, 256, 0, stream>>>(W1, Wg, batch, start);
  scores_mfma<<<512, 256, 0, stream>>>(x, Wg, b1, w2, b2, scores);
  pool_kernel<<<NG, 256, 0, stream>>>(x, scores, start, out);
}

// Round 5
// 131.241 us; speedup vs baseline: 3.1062x; 1.6311x over previous
//
#include <hip/hip_runtime.h>
#include <math.h>

#define NN 500000
#define CH 128
#define NG 1024
#define GRID 256
#define NTILES ((NN + 127) >> 7)   // 3907 tiles of 128 rows

typedef __attribute__((ext_vector_type(8))) short short8v;
typedef __attribute__((ext_vector_type(4))) float f32x4;

__device__ __forceinline__ float wred_max64(float v){
  #pragma unroll
  for (int o = 32; o; o >>= 1) v = fmaxf(v, __shfl_xor(v, o));
  return v;
}

__device__ __forceinline__ void bf16_split(float f, unsigned short& h, unsigned short& l){
  const unsigned u = __float_as_uint(f);
  h = (unsigned short)(u >> 16);
  const float hif = __uint_as_float(u & 0xffff0000u);
  const float lof = f - hif;
  l = (unsigned short)(__float_as_uint(lof) >> 16);
}

// async global->LDS, 16B per lane. LDS dest must be wave-uniform base + lane*16.
__device__ __forceinline__ void gld_lds16(const void* g, void* l){
  __builtin_amdgcn_global_load_lds(
      (__attribute__((address_space(1))) void*)g,
      (__attribute__((address_space(3))) void*)l, 16, 0, 0);
}

// Prep: (a) t<2048: transpose + bf16-hi/lo-split W1 into Wg (swizzled LDS byte
// order). (b) t in [2048, 2048+NG]: segment boundaries via lower_bound.
__global__ __launch_bounds__(256) void prep_kernel(
    const float* __restrict__ W1, unsigned short* __restrict__ Wg,
    const int* __restrict__ batch, int* __restrict__ start){
  const int t = blockIdx.x * 256 + threadIdx.x;
  if (t < 2048){
    const int n  = t >> 4;          // out-channel 0..127
    const int k0 = (t & 15) << 3;   // 0,8,...,120
    unsigned short hv[8], lv[8];
    #pragma unroll
    for (int i = 0; i < 8; i++)
      bf16_split(W1[(size_t)(k0 + i) * CH + n], hv[i], lv[i]);
    const int byte = (n * 256 + k0 * 2) ^ ((n & 7) << 4);   // XOR swizzle, 16B granule
    *reinterpret_cast<short8v*>(reinterpret_cast<char*>(Wg) + byte) =
        *reinterpret_cast<short8v*>(hv);
    *reinterpret_cast<short8v*>(reinterpret_cast<char*>(Wg) + 32768 + byte) =
        *reinterpret_cast<short8v*>(lv);
  } else if (t <= 2048 + NG){
    const int g = t - 2048;
    const bool is64 = (batch[NN - 1] == 0);   // int64-vs-int32 runtime hedge
    if (g == NG){ start[NG] = NN; return; }
    int lo = 0, hi = NN;
    while (lo < hi){
      int mid = (lo + hi) >> 1;
      int v = is64 ? batch[2 * mid] : batch[mid];
      if (v < g) lo = mid + 1; else hi = mid;
    }
    start[g] = lo;
  }
}

// K1: scores = relu(x@W1 + b1).w2 + b2, 3-term bf16-split MFMA.
// global_load_lds double-buffered x staging (half-K units of 128 rows x 64 k),
// 2-phase pipeline: stage(next) -> compute(cur) -> vmcnt(0) -> barrier.
__global__ __launch_bounds__(256, 1) void scores_mfma(
    const float* __restrict__ x, const unsigned short* __restrict__ Wg,
    const float* __restrict__ b1, const float* __restrict__ w2,
    const float* __restrict__ b2, float* __restrict__ scores)
{
  __shared__ unsigned short WB[2 * CH * CH];   // 64KB: W^T hi | lo, swizzled
  __shared__ float XS[2 * 8192];               // 64KB: two 128x64 fp32 x-buffers
  __shared__ float b1s[CH], w2s[CH];

  const int tid = threadIdx.x;
  const int w   = tid >> 6;    // wave 0..3
  const int l   = tid & 63;
  const int l15 = l & 15;
  const int g   = l >> 4;      // 0..3

  // Stage W (pre-split, coalesced, conflict-free), once.
  {
    const short8v* __restrict__ src = reinterpret_cast<const short8v*>(Wg);
    short8v* dst = reinterpret_cast<short8v*>(WB);
    #pragma unroll
    for (int it = 0; it < 16; ++it)
      dst[it * 256 + tid] = src[it * 256 + tid];
  }
  if (tid < CH){ b1s[tid] = b1[tid]; w2s[tid] = w2[tid]; }

  const char* const WhB = reinterpret_cast<const char*>(WB);
  const char* const WlB = reinterpret_cast<const char*>(WB) + 32768;
  const float b2v = b2[0];

  const int bid = blockIdx.x;
  const int ntb = (NTILES - 1 - bid) / GRID + 1;   // tiles for this block

  // Stage one half-K unit: 128 rows x 64 floats -> buffer kh (linear LDS dest,
  // inverse-swizzled global source; stored[R][c] = row chunk (c ^ (R&15))).
  const int r0 = tid >> 4;          // 0..15
  const int c  = tid & 15;
  const int cswz = (c ^ r0) << 4;   // byte offset of source chunk within half-row
  auto stage = [&](int tt, int kh){
    char* ldsb = (char*)XS + kh * 32768;
    #pragma unroll
    for (int q = 0; q < 8; ++q){
      const int R = q * 16 + r0;
      int row = tt * 128 + R;
      row = row < NN ? row : NN - 1;            // clamp (stores guarded)
      const char* gsrc = (const char*)x + (size_t)row * 512 + kh * 256 + cswz;
      gld_lds16(gsrc, ldsb + q * 4096 + tid * 16);
    }
  };

  stage(bid, 0);
  __syncthreads();   // drains vmcnt + lgkmcnt; WB/b1s/w2s ready

  for (int ti = 0; ti < ntb; ++ti){
    const int tt = bid + ti * GRID;

    stage(tt, 1);                                // kh=1 half in flight

    f32x4 acc[2][8];
    #pragma unroll
    for (int a = 0; a < 2; a++)
      #pragma unroll
      for (int b = 0; b < 8; b++) acc[a][b] = (f32x4)0.f;

    #pragma unroll
    for (int kh = 0; kh < 2; ++kh){
      const char* xbB = (const char*)XS + kh * 32768;
      #pragma unroll
      for (int kcl = 0; kcl < 2; ++kcl){
        const int kcg = kh * 2 + kcl;
        // A fragments from LDS: lane l -> x[R = w*32+nt*16+l15][k = kcg*32+g*8+j]
        short8v Ah[2], Al[2];
        #pragma unroll
        for (int nt = 0; nt < 2; nt++){
          const int R = w * 32 + nt * 16 + l15;
          const int s0 = kcl * 8 + g * 2;
          float fv[8];
          *reinterpret_cast<float4*>(fv) = *reinterpret_cast<const float4*>(
              xbB + R * 256 + (((s0)     ^ l15) << 4));
          *reinterpret_cast<float4*>(fv + 4) = *reinterpret_cast<const float4*>(
              xbB + R * 256 + (((s0 + 1) ^ l15) << 4));
          unsigned short hv[8], lv[8];
          #pragma unroll
          for (int j = 0; j < 8; j++) bf16_split(fv[j], hv[j], lv[j]);
          Ah[nt] = *reinterpret_cast<short8v*>(hv);
          Al[nt] = *reinterpret_cast<short8v*>(lv);
        }
        #pragma unroll
        for (int ct = 0; ct < 8; ct++){
          const int n = ct * 16 + l15;
          const int byte = (n * 256 + kcg * 64 + g * 16) ^ ((n & 7) << 4);
          const short8v Bh = *reinterpret_cast<const short8v*>(WhB + byte);
          const short8v Bl = *reinterpret_cast<const short8v*>(WlB + byte);
          #pragma unroll
          for (int nt = 0; nt < 2; nt++){
            acc[nt][ct] = __builtin_amdgcn_mfma_f32_16x16x32_bf16(Ah[nt], Bh, acc[nt][ct], 0, 0, 0);
            acc[nt][ct] = __builtin_amdgcn_mfma_f32_16x16x32_bf16(Al[nt], Bh, acc[nt][ct], 0, 0, 0);
            acc[nt][ct] = __builtin_amdgcn_mfma_f32_16x16x32_bf16(Ah[nt], Bl, acc[nt][ct], 0, 0, 0);
          }
        }
      }
      if (kh == 0){
        // kh=1 loads landed; everyone done reading buf0 -> safe to restage it.
        asm volatile("s_waitcnt vmcnt(0)" ::: "memory");
        __builtin_amdgcn_s_barrier();
        __builtin_amdgcn_sched_barrier(0);
        if (ti + 1 < ntb) stage(bid + (ti + 1) * GRID, 0);   // next tile kh=0
      }
    }

    // Epilogue: s = relu(H+b1).w2 ; shuffle-transpose so lanes 0-31 hold
    // consecutive rows, then one coalesced 128B store per wave.
    float myval = 0.f;
    #pragma unroll
    for (int nt = 0; nt < 2; nt++){
      #pragma unroll
      for (int r = 0; r < 4; r++){
        float s = 0.f;
        #pragma unroll
        for (int ct = 0; ct < 8; ct++){
          const int n = ct * 16 + l15;
          float h = acc[nt][ct][r] + b1s[n];
          h = fmaxf(h, 0.f);
          s = fmaf(h, w2s[n], s);
        }
        s += __shfl_xor(s, 1); s += __shfl_xor(s, 2);
        s += __shfl_xor(s, 4); s += __shfl_xor(s, 8);   // all 16 lanes hold group sum
        // lane j<32 wants (nt,g,r) = (j>>4, (j>>2)&3, j&3), value lives in group g
        const float got = __shfl(s, ((l >> 2) & 3) << 4);
        if (((l >> 4) == nt) && ((l & 3) == r)) myval = got;
      }
    }
    const int srow = tt * 128 + w * 32 + l;
    if (l < 32 && srow < NN) scores[srow] = myval + b2v;

    asm volatile("s_waitcnt vmcnt(0)" ::: "memory");
    __builtin_amdgcn_s_barrier();
    __builtin_amdgcn_sched_barrier(0);
  }
}

// K3 (fused softmax+pool): out[g] = sum_i e_i*x_i / sum_i e_i, e_i = exp(s_i - max_g)
__global__ __launch_bounds__(256) void pool_kernel(
    const float* __restrict__ x, const float* __restrict__ sc,
    const int* __restrict__ start, float* __restrict__ out){
  const int g = blockIdx.x;
  const int s0 = start[g], s1 = start[g + 1];
  const int tid = threadIdx.x;

  __shared__ float tmp[4];
  __shared__ float bval;

  float m = -INFINITY;
  for (int i = s0 + tid; i < s1; i += 256) m = fmaxf(m, sc[i]);
  m = wred_max64(m);
  if ((tid & 63) == 0) tmp[tid >> 6] = m;
  __syncthreads();
  if (tid == 0) bval = fmaxf(fmaxf(tmp[0], tmp[1]), fmaxf(tmp[2], tmp[3]));
  __syncthreads();
  m = bval;

  const int c4 = tid & 31;   // float4 column
  const int rg = tid >> 5;   // row group 0..7
  float4 acc = make_float4(0.f, 0.f, 0.f, 0.f);
  float den = 0.f;
  for (int i = s0 + rg; i < s1; i += 8){
    const float e = __expf(sc[i] - m);
    den += e;
    const float4 xv = reinterpret_cast<const float4*>(&x[(size_t)i * CH])[c4];
    acc.x = fmaf(e, xv.x, acc.x);
    acc.y = fmaf(e, xv.y, acc.y);
    acc.z = fmaf(e, xv.z, acc.z);
    acc.w = fmaf(e, xv.w, acc.w);
  }

  __shared__ float4 red[8][32];
  __shared__ float redd[8][32];
  red[rg][c4] = acc;
  redd[rg][c4] = den;
  __syncthreads();
  if (rg < 4){
    float4 o = red[rg + 4][c4], mm = red[rg][c4];
    mm.x += o.x; mm.y += o.y; mm.z += o.z; mm.w += o.w;
    red[rg][c4] = mm;
    redd[rg][c4] += redd[rg + 4][c4];
  }
  __syncthreads();
  if (rg < 2){
    float4 o = red[rg + 2][c4], mm = red[rg][c4];
    mm.x += o.x; mm.y += o.y; mm.z += o.z; mm.w += o.w;
    red[rg][c4] = mm;
    redd[rg][c4] += redd[rg + 2][c4];
  }
  __syncthreads();
  if (rg == 0){
    float4 a0 = red[0][c4], a1 = red[1][c4];
    const float d = redd[0][c4] + redd[1][c4];
    const float inv = d > 0.f ? 1.f / d : 0.f;
    float4 r;
    r.x = (a0.x + a1.x) * inv; r.y = (a0.y + a1.y) * inv;
    r.z = (a0.z + a1.z) * inv; r.w = (a0.w + a1.w) * inv;
    reinterpret_cast<float4*>(&out[(size_t)g * CH])[c4] = r;
  }
}

extern "C" void kernel_launch(void* const* d_in, const int* in_sizes, int n_in,
                              void* d_out, int out_size, void* d_ws, size_t ws_size,
                              hipStream_t stream){
  const float* x    = (const float*)d_in[0];
  const int*   batch= (const int*)d_in[1];
  const float* W1   = (const float*)d_in[2];
  const float* b1   = (const float*)d_in[3];
  const float* w2   = (const float*)d_in[4];
  const float* b2   = (const float*)d_in[5];
  float* out = (float*)d_out;

  float* scores = (float*)d_ws;                                     // NN floats
  int*   start  = (int*)((char*)d_ws + (size_t)NN * sizeof(float)); // NG+1 ints
  unsigned short* Wg = (unsigned short*)((char*)d_ws + ((ws_size - 65536) & ~(size_t)255));

  prep_kernel<<<13, 256, 0, stream>>>(W1, Wg, batch, start);
  scores_mfma<<<GRID, 256, 0, stream>>>(x, Wg, b1, w2, b2, scores);
  pool_kernel<<<NG, 256, 0, stream>>>(x, scores, start, out);
}